// Round 6
// baseline (200.586 us; speedup 1.0000x reference)
//
#include <hip/hip_runtime.h>

// XMaskSwitchTop2Hard: per-4-group top-2 hard gate mixed with sigmoid(gate_logits).
// Forward math: gate_raw = gate_hard - sg(gate_soft) + gate_soft == gate_hard
// (up to ~1 ulp of gate_soft <= 2.4e-7, far below the 0.108 absmax threshold),
// so softmax is skipped. out[j] = keep_j ? x_j : r[g]*x_j, with top_k's
// lowest-index-wins tie-break replicated via stable ranking.
//
// R6: deepen MLP 4 -> 8 (R5's 4x block-contiguous unroll confirmed the
// latency-hiding theory, 216->200us). 8 independent loads in flight per
// thread before any dependent store; block macro-span 32KB contiguous.
// Gate index offsets (k*256 + tid) mod 1024 have period 4 -> r0..r3 reused.

#define GROUPS_PER_ROW 1024  // 4096 hidden / GROUP=4

typedef float f4 __attribute__((ext_vector_type(4)));

__device__ __forceinline__ f4 gate_group(f4 v, float r) {
    float s0 = fabsf(v.x), s1 = fabsf(v.y), s2 = fabsf(v.z), s3 = fabsf(v.w);
    // rank_j = count of i beating j; i beats j iff s_i > s_j, or tie with i<j.
    int c0 = (s1 >  s0) + (s2 >  s0) + (s3 >  s0);
    int c1 = (s0 >= s1) + (s2 >  s1) + (s3 >  s1);
    int c2 = (s0 >= s2) + (s1 >= s2) + (s3 >  s2);
    int c3 = (s0 >= s3) + (s1 >= s3) + (s2 >= s3);
    f4 o;
    o.x = (c0 < 2) ? v.x : r * v.x;
    o.y = (c1 < 2) ? v.y : r * v.y;
    o.z = (c2 < 2) ? v.z : r * v.z;
    o.w = (c3 < 2) ? v.w : r * v.w;
    return o;
}

__device__ __forceinline__ float sigmoidf_(float x) {
    return 1.0f / (1.0f + expf(-x));
}

__global__ __launch_bounds__(256)
void xmask_top2_kernel(const f4* __restrict__ x4,
                       const float* __restrict__ gate_logits,
                       f4* __restrict__ out4,
                       int ngroups) {
    const int tid = threadIdx.x;

    // Offsets k*256+tid (k=0..7) mod 1024 cycle with period 4.
    float r0 = sigmoidf_(gate_logits[tid]);
    float r1 = sigmoidf_(gate_logits[tid + 256]);
    float r2 = sigmoidf_(gate_logits[tid + 512]);
    float r3 = sigmoidf_(gate_logits[tid + 768]);

    const int macro = gridDim.x * 2048;          // 4194304 groups / macro-iter
    int g = blockIdx.x * 2048 + tid;

    for (; g + 1792 < ngroups; g += macro) {
        f4 v0 = x4[g];
        f4 v1 = x4[g + 256];
        f4 v2 = x4[g + 512];
        f4 v3 = x4[g + 768];
        f4 v4 = x4[g + 1024];
        f4 v5 = x4[g + 1280];
        f4 v6 = x4[g + 1536];
        f4 v7 = x4[g + 1792];

        out4[g]        = gate_group(v0, r0);
        out4[g + 256]  = gate_group(v1, r1);
        out4[g + 512]  = gate_group(v2, r2);
        out4[g + 768]  = gate_group(v3, r3);
        out4[g + 1024] = gate_group(v4, r0);
        out4[g + 1280] = gate_group(v5, r1);
        out4[g + 1536] = gate_group(v6, r2);
        out4[g + 1792] = gate_group(v7, r3);
    }
    // Tail (not taken for the fixed 33554432-group problem, kept for safety).
    for (; g < ngroups; g += 256) {
        float r = sigmoidf_(gate_logits[g & (GROUPS_PER_ROW - 1)]);
        out4[g] = gate_group(x4[g], r);
    }
}

extern "C" void kernel_launch(void* const* d_in, const int* in_sizes, int n_in,
                              void* d_out, int out_size, void* d_ws, size_t ws_size,
                              hipStream_t stream) {
    const f4* x4 = (const f4*)d_in[0];
    const float* gate_logits = (const float*)d_in[1];
    f4* out4 = (f4*)d_out;

    int ngroups = out_size / 4;  // 134217728 / 4 = 33554432

    const int threads = 256;
    const int blocks = 2048;  // macro stride = 4194304, 8 macro-iters exactly
    xmask_top2_kernel<<<blocks, threads, 0, stream>>>(x4, gate_logits, out4, ngroups);
}

// Round 7
// 193.969 us; speedup vs baseline: 1.0341x; 1.0341x over previous
//
#include <hip/hip_runtime.h>

// XMaskSwitchTop2Hard: per-4-group top-2 hard gate mixed with sigmoid(gate_logits).
// Forward math: gate_raw = gate_hard - sg(gate_soft) + gate_soft == gate_hard
// (up to ~1 ulp of gate_soft <= 2.4e-7, far below the 0.108 absmax threshold),
// so softmax is skipped. out[j] = keep_j ? x_j : r[g]*x_j, with top_k's
// lowest-index-wins tie-break replicated via stable ranking.
//
// R7: exact R5 structure (4x block-contiguous unroll — best so far, 199.6us)
// + ONE change: nontemporal stores (output is write-once never-read; skip
// L2/L3 write allocation so dirty-line flushes don't contend with fetches).
// Clean A/B vs R5; R3's NT-store test was confounded with a bad unroll.

#define GROUPS_PER_ROW 1024  // 4096 hidden / GROUP=4

typedef float f4 __attribute__((ext_vector_type(4)));

__device__ __forceinline__ f4 gate_group(f4 v, float r) {
    float s0 = fabsf(v.x), s1 = fabsf(v.y), s2 = fabsf(v.z), s3 = fabsf(v.w);
    // rank_j = count of i beating j; i beats j iff s_i > s_j, or tie with i<j.
    int c0 = (s1 >  s0) + (s2 >  s0) + (s3 >  s0);
    int c1 = (s0 >= s1) + (s2 >  s1) + (s3 >  s1);
    int c2 = (s0 >= s2) + (s1 >= s2) + (s3 >  s2);
    int c3 = (s0 >= s3) + (s1 >= s3) + (s2 >= s3);
    f4 o;
    o.x = (c0 < 2) ? v.x : r * v.x;
    o.y = (c1 < 2) ? v.y : r * v.y;
    o.z = (c2 < 2) ? v.z : r * v.z;
    o.w = (c3 < 2) ? v.w : r * v.w;
    return o;
}

__device__ __forceinline__ float sigmoidf_(float x) {
    return 1.0f / (1.0f + expf(-x));
}

__global__ __launch_bounds__(256)
void xmask_top2_kernel(const f4* __restrict__ x4,
                       const float* __restrict__ gate_logits,
                       f4* __restrict__ out4,
                       int ngroups) {
    const int tid = threadIdx.x;

    // Macro stride is a multiple of 1024, so each subiteration's gate group
    // index is loop-invariant per thread.
    float r0 = sigmoidf_(gate_logits[tid]);
    float r1 = sigmoidf_(gate_logits[tid + 256]);
    float r2 = sigmoidf_(gate_logits[tid + 512]);
    float r3 = sigmoidf_(gate_logits[tid + 768]);

    const int macro = gridDim.x * 1024;          // 2097152 groups / macro-iter
    int g = blockIdx.x * 1024 + tid;

    for (; g + 768 < ngroups; g += macro) {
        f4 v0 = x4[g];
        f4 v1 = x4[g + 256];
        f4 v2 = x4[g + 512];
        f4 v3 = x4[g + 768];

        __builtin_nontemporal_store(gate_group(v0, r0), &out4[g]);
        __builtin_nontemporal_store(gate_group(v1, r1), &out4[g + 256]);
        __builtin_nontemporal_store(gate_group(v2, r2), &out4[g + 512]);
        __builtin_nontemporal_store(gate_group(v3, r3), &out4[g + 768]);
    }
    // Tail (not taken for the fixed 33554432-group problem, kept for safety).
    for (; g < ngroups; g += 256) {
        float r = sigmoidf_(gate_logits[g & (GROUPS_PER_ROW - 1)]);
        __builtin_nontemporal_store(gate_group(x4[g], r), &out4[g]);
    }
}

extern "C" void kernel_launch(void* const* d_in, const int* in_sizes, int n_in,
                              void* d_out, int out_size, void* d_ws, size_t ws_size,
                              hipStream_t stream) {
    const f4* x4 = (const f4*)d_in[0];
    const float* gate_logits = (const float*)d_in[1];
    f4* out4 = (f4*)d_out;

    int ngroups = out_size / 4;  // 134217728 / 4 = 33554432

    const int threads = 256;
    const int blocks = 2048;  // macro stride = 2097152, 16 macro-iters exactly
    xmask_top2_kernel<<<blocks, threads, 0, stream>>>(x4, gate_logits, out4, ngroups);
}

// Round 8
// 184.001 us; speedup vs baseline: 1.0901x; 1.0542x over previous
//
#include <hip/hip_runtime.h>

// XMaskSwitchTop2Hard: per-4-group top-2 hard gate mixed with sigmoid(gate_logits).
// Forward math: gate_raw = gate_hard - sg(gate_soft) + gate_soft == gate_hard
// (up to ~1 ulp of gate_soft <= 2.4e-7, far below the 0.108 absmax threshold),
// so softmax is skipped. out[j] = keep_j ? x_j : r[g]*x_j, with top_k's
// lowest-index-wins tie-break replicated via stable ranking.
//
// R8: exact R7 structure (4x unroll + NT stores, 194.0us) + ONE change:
// nontemporal LOADS as well — read stream is touch-once, skip L2/L3
// allocation on the fetch path too. Final single-variable probe before
// declaring the mixed-stream roofline.

#define GROUPS_PER_ROW 1024  // 4096 hidden / GROUP=4

typedef float f4 __attribute__((ext_vector_type(4)));

__device__ __forceinline__ f4 gate_group(f4 v, float r) {
    float s0 = fabsf(v.x), s1 = fabsf(v.y), s2 = fabsf(v.z), s3 = fabsf(v.w);
    // rank_j = count of i beating j; i beats j iff s_i > s_j, or tie with i<j.
    int c0 = (s1 >  s0) + (s2 >  s0) + (s3 >  s0);
    int c1 = (s0 >= s1) + (s2 >  s1) + (s3 >  s1);
    int c2 = (s0 >= s2) + (s1 >= s2) + (s3 >  s2);
    int c3 = (s0 >= s3) + (s1 >= s3) + (s2 >= s3);
    f4 o;
    o.x = (c0 < 2) ? v.x : r * v.x;
    o.y = (c1 < 2) ? v.y : r * v.y;
    o.z = (c2 < 2) ? v.z : r * v.z;
    o.w = (c3 < 2) ? v.w : r * v.w;
    return o;
}

__device__ __forceinline__ float sigmoidf_(float x) {
    return 1.0f / (1.0f + expf(-x));
}

__global__ __launch_bounds__(256)
void xmask_top2_kernel(const f4* __restrict__ x4,
                       const float* __restrict__ gate_logits,
                       f4* __restrict__ out4,
                       int ngroups) {
    const int tid = threadIdx.x;

    // Macro stride is a multiple of 1024, so each subiteration's gate group
    // index is loop-invariant per thread.
    float r0 = sigmoidf_(gate_logits[tid]);
    float r1 = sigmoidf_(gate_logits[tid + 256]);
    float r2 = sigmoidf_(gate_logits[tid + 512]);
    float r3 = sigmoidf_(gate_logits[tid + 768]);

    const int macro = gridDim.x * 1024;          // 2097152 groups / macro-iter
    int g = blockIdx.x * 1024 + tid;

    for (; g + 768 < ngroups; g += macro) {
        f4 v0 = __builtin_nontemporal_load(&x4[g]);
        f4 v1 = __builtin_nontemporal_load(&x4[g + 256]);
        f4 v2 = __builtin_nontemporal_load(&x4[g + 512]);
        f4 v3 = __builtin_nontemporal_load(&x4[g + 768]);

        __builtin_nontemporal_store(gate_group(v0, r0), &out4[g]);
        __builtin_nontemporal_store(gate_group(v1, r1), &out4[g + 256]);
        __builtin_nontemporal_store(gate_group(v2, r2), &out4[g + 512]);
        __builtin_nontemporal_store(gate_group(v3, r3), &out4[g + 768]);
    }
    // Tail (not taken for the fixed 33554432-group problem, kept for safety).
    for (; g < ngroups; g += 256) {
        float r = sigmoidf_(gate_logits[g & (GROUPS_PER_ROW - 1)]);
        __builtin_nontemporal_store(gate_group(__builtin_nontemporal_load(&x4[g]), r), &out4[g]);
    }
}

extern "C" void kernel_launch(void* const* d_in, const int* in_sizes, int n_in,
                              void* d_out, int out_size, void* d_ws, size_t ws_size,
                              hipStream_t stream) {
    const f4* x4 = (const f4*)d_in[0];
    const float* gate_logits = (const float*)d_in[1];
    f4* out4 = (f4*)d_out;

    int ngroups = out_size / 4;  // 134217728 / 4 = 33554432

    const int threads = 256;
    const int blocks = 2048;  // macro stride = 2097152, 16 macro-iters exactly
    xmask_top2_kernel<<<blocks, threads, 0, stream>>>(x4, gate_logits, out4, ngroups);
}